// Round 3
// baseline (5813.119 us; speedup 1.0000x reference)
//
#include <hip/hip_runtime.h>
#include <math.h>

#define BB 32
#define CC 256
#define HWt 1024          // H*W
#define NN 32768          // B*H*W
#define KK 2048
#define RQDEPTH 4

// ===== numpy pairwise sum-of-squares, blocksize-128 tree, bit-exact =====
__device__ __forceinline__ float pw128sq(const float4* __restrict__ a4) {
  float r[8];
  {
    float4 p = a4[0], q = a4[1];
    r[0] = __fmul_rn(p.x, p.x); r[1] = __fmul_rn(p.y, p.y);
    r[2] = __fmul_rn(p.z, p.z); r[3] = __fmul_rn(p.w, p.w);
    r[4] = __fmul_rn(q.x, q.x); r[5] = __fmul_rn(q.y, q.y);
    r[6] = __fmul_rn(q.z, q.z); r[7] = __fmul_rn(q.w, q.w);
  }
  for (int i = 1; i < 16; ++i) {
    float4 p = a4[2 * i], q = a4[2 * i + 1];
    r[0] = __fadd_rn(r[0], __fmul_rn(p.x, p.x));
    r[1] = __fadd_rn(r[1], __fmul_rn(p.y, p.y));
    r[2] = __fadd_rn(r[2], __fmul_rn(p.z, p.z));
    r[3] = __fadd_rn(r[3], __fmul_rn(p.w, p.w));
    r[4] = __fadd_rn(r[4], __fmul_rn(q.x, q.x));
    r[5] = __fadd_rn(r[5], __fmul_rn(q.y, q.y));
    r[6] = __fadd_rn(r[6], __fmul_rn(q.z, q.z));
    r[7] = __fadd_rn(r[7], __fmul_rn(q.w, q.w));
  }
  return __fadd_rn(__fadd_rn(__fadd_rn(r[0], r[1]), __fadd_rn(r[2], r[3])),
                   __fadd_rn(__fadd_rn(r[4], r[5]), __fadd_rn(r[6], r[7])));
}

// ---------------- prep: z [B,C,H,W] -> resid [N,C] ----------------
__global__ void k_ztrans(const float* __restrict__ z, float* __restrict__ resid) {
  __shared__ float tile[32][33];
  int b = blockIdx.z, c0 = blockIdx.y * 32, hw0 = blockIdx.x * 32;
  int tx = threadIdx.x & 31, ty = threadIdx.x >> 5;
  for (int i = ty; i < 32; i += 8)
    tile[i][tx] = z[((size_t)b * CC + c0 + i) * HWt + hw0 + tx];
  __syncthreads();
  for (int i = ty; i < 32; i += 8)
    resid[((size_t)b * HWt + hw0 + i) * CC + c0 + tx] = tile[tx][i];
}

// ---------------- prep: cb [K,C] -> cbT [C,K] ----------------
__global__ void k_cbtrans(const float* __restrict__ cb, float* __restrict__ cbT) {
  __shared__ float tile[32][33];
  int k0 = blockIdx.x * 32, c0 = blockIdx.y * 32;
  int tx = threadIdx.x & 31, ty = threadIdx.x >> 5;
  for (int i = ty; i < 32; i += 8)
    tile[i][tx] = cb[(size_t)(k0 + i) * CC + c0 + tx];
  __syncthreads();
  for (int i = ty; i < 32; i += 8)
    cbT[(size_t)(c0 + i) * KK + k0 + tx] = tile[tx][i];
}

// ---------------- B_k = np.sum(cb**2, axis=1) bit-exact ----------------
__global__ void k_bnorm(const float* __restrict__ cb, float* __restrict__ Bcol) {
  int k = blockIdx.x * 256 + threadIdx.x;
  if (k >= KK) return;
  const float4* row = (const float4*)(cb + (size_t)k * CC);
  Bcol[k] = __fadd_rn(pw128sq(row), pw128sq(row + 32));
}

// ---------------- A_n = np.sum(resid**2, axis=1) bit-exact ----------------
__global__ void k_anorm(const float* __restrict__ resid, float* __restrict__ Arow) {
  int n = blockIdx.x * 256 + threadIdx.x;
  if (n >= NN) return;
  const float4* row = (const float4*)(resid + (size_t)n * CC);
  Arow[n] = __fadd_rn(pw128sq(row), pw128sq(row + 32));
}

__global__ void k_zero(int* counts) {
  int t = blockIdx.x * 256 + threadIdx.x;
  if (t < KK) counts[t] = 0;
}

// ---------------- bulk: np fp32 dists + first-argmin ----------------
// Round-0 structure exactly (single E buffer, no prefetch pipeline -- that
// register schedule is the verified spill-free one: VGPR 52 + AGPR-backed acc).
// ONE change vs round 0: z is served from a 16 KB LDS tile staged once per
// block, read with a full-wave-uniform address (hardware broadcast, 0 bank
// conflicts), instead of 16 wave-uniform s_load_dwordx4 per c4-iteration that
// thrash the 16 KB per-CU scalar cache across 3-4 resident blocks. Per-(n,k)
// fp32 chain is bit-identical: strict c-ascending fmaf, fl(A+B) - 2*acc, u64
// (dist,k) min == exact lex first-argmin.
__global__ __launch_bounds__(256, 4) void k_bulk(const float* __restrict__ resid,
                                                 const float* __restrict__ cbT,
                                                 const float* __restrict__ Arow,
                                                 const float* __restrict__ Bcol,
                                                 int* __restrict__ idxAll,
                                                 float* __restrict__ idxOut,
                                                 int* __restrict__ counts, int depth) {
  __shared__ float zl[16 * 256];                 // 16 KiB z tile
  __shared__ unsigned long long sm[4][2][16];
  const int wave = __builtin_amdgcn_readfirstlane((int)(threadIdx.x >> 6));
  const int lane = threadIdx.x & 63;
  const int row0 = blockIdx.x * 16;

  // stage z tile -> LDS (coalesced float4, 4 per thread)
  {
    const float4* src = (const float4*)(resid + (size_t)row0 * CC);
    float4* dst = (float4*)zl;
#pragma unroll
    for (int i = 0; i < 4; ++i)
      dst[threadIdx.x + 256 * i] = src[threadIdx.x + 256 * i];
  }

  float av[16];
#pragma unroll
  for (int r = 0; r < 16; ++r) av[r] = Arow[row0 + r];   // uniform -> SGPR

  __syncthreads();

  for (int pass = 0; pass < 2; ++pass) {
    const int kbase = wave * 512 + pass * 256;
    float acc[16][4];
#pragma unroll
    for (int r = 0; r < 16; ++r)
#pragma unroll
      for (int j = 0; j < 4; ++j) acc[r][j] = 0.f;

    for (int c4 = 0; c4 < CC / 4; ++c4) {
      float e[16];  // [cs][j]
#pragma unroll
      for (int cs = 0; cs < 4; ++cs)
        *(float4*)(e + 4 * cs) =
            ((const float4*)(cbT + (size_t)(4 * c4 + cs) * KK + kbase))[lane];
#pragma unroll
      for (int r = 0; r < 16; ++r) {
        const float4 z4 = *(const float4*)(zl + r * 256 + 4 * c4);  // LDS broadcast
#pragma unroll
        for (int j = 0; j < 4; ++j) {
          float a = acc[r][j];
          a = fmaf(z4.x, e[0 * 4 + j], a);   // strict c-ascending chain (sgemm order)
          a = fmaf(z4.y, e[1 * 4 + j], a);
          a = fmaf(z4.z, e[2 * 4 + j], a);
          a = fmaf(z4.w, e[3 * 4 + j], a);
          acc[r][j] = a;
        }
      }
    }
    // epilogue: dists + exact lex first-argmin for this pass
    float bk[4];
    *(float4*)bk = ((const float4*)(Bcol + kbase))[lane];
#pragma unroll
    for (int r = 0; r < 16; ++r) {
      unsigned long long b = ~0ull;
#pragma unroll
      for (int j = 0; j < 4; ++j) {
        float Cv = __fadd_rn(av[r], bk[j]);                      // fl32(A + B)
        float s  = __fsub_rn(Cv, __fadd_rn(acc[r][j], acc[r][j]));  // fl32(C - 2M)
        unsigned long long pk =
            ((unsigned long long)__float_as_uint(s) << 32) |
            (unsigned int)(kbase + lane * 4 + j);
        if (pk < b) b = pk;
      }
      for (int m = 1; m < 64; m <<= 1) {
        unsigned long long o = __shfl_xor(b, m);
        if (o < b) b = o;
      }
      if (lane == 0) sm[wave][pass][r] = b;
    }
  }
  __syncthreads();
  // merge 4 waves x 2 passes per row
  if (threadIdx.x < 16) {
    unsigned long long b = ~0ull;
#pragma unroll
    for (int w = 0; w < 4; ++w)
#pragma unroll
      for (int p = 0; p < 2; ++p)
        if (sm[w][p][threadIdx.x] < b) b = sm[w][p][threadIdx.x];
    int wi = (int)(unsigned int)(b & 0xffffffffu);
    int n = row0 + (int)threadIdx.x;
    idxAll[depth * NN + n] = wi;
    idxOut[n] = (float)wi;
    atomicAdd(counts + wi, 1);
  }
}

// ------- update: resid -= q (fp32, np order), cum[d] = cum[d-1] + q, zst at d=3 -------
__global__ void k_update(const float* __restrict__ cb, const int* __restrict__ idxAll,
                         float* __restrict__ resid, float* __restrict__ cum,
                         float* __restrict__ zst, int depth) {
  __shared__ float qt[32][33];
  __shared__ float rt[32][33];
  int b = blockIdx.z, c0 = blockIdx.y * 32, hw0 = blockIdx.x * 32;
  int tx = threadIdx.x & 31, ty = threadIdx.x >> 5;
  const int* idx = idxAll + depth * NN;
  for (int i = ty; i < 32; i += 8) {
    int n = b * HWt + hw0 + i;
    int kk = idx[n];
    size_t fo = (size_t)n * CC + c0 + tx;
    float q = cb[(size_t)kk * CC + c0 + tx];
    float r = __fsub_rn(resid[fo], q);
    resid[fo] = r;
    qt[i][tx] = q;
    rt[i][tx] = r;
  }
  __syncthreads();
  const size_t PLANE = (size_t)NN * CC;
  for (int i = ty; i < 32; i += 8) {
    size_t oo = ((size_t)b * CC + c0 + i) * HWt + hw0 + tx;
    float q = qt[tx][i];
    float prevv = (depth == 0) ? 0.f : cum[(size_t)(depth - 1) * PLANE + oo];
    cum[(size_t)depth * PLANE + oo] = __fadd_rn(prevv, q);
    if (depth == 3) zst[oo] = rt[tx][i];
  }
}

// ---------------- perplexity ----------------
__global__ void k_perp(const int* __restrict__ counts, float* __restrict__ out) {
  __shared__ double sh[256];
  double s = 0.0;
  for (int k = threadIdx.x; k < KK; k += 256) {
    int c = counts[k];
    if (c > 0) {
      double p = (double)c / (double)(RQDEPTH * NN);
      s += p * log(p);
    }
  }
  sh[threadIdx.x] = s;
  __syncthreads();
  for (int st = 128; st; st >>= 1) {
    if (threadIdx.x < st) sh[threadIdx.x] += sh[threadIdx.x + st];
    __syncthreads();
  }
  if (threadIdx.x == 0) out[0] = (float)exp(-sh[0]);
}

extern "C" void kernel_launch(void* const* d_in, const int* in_sizes, int n_in,
                              void* d_out, int out_size, void* d_ws, size_t ws_size,
                              hipStream_t stream) {
  const float* z  = (const float*)d_in[0];
  const float* cb = (const float*)d_in[1];
  float* out = (float*)d_out;
  const size_t PLANE = (size_t)NN * CC;          // 8,388,608
  float* cum  = out;                             // [4][B][C][H][W]
  float* zst  = out + (size_t)RQDEPTH * PLANE;   // [B][C][H][W]
  float* idxo = zst + PLANE;                     // [4][N]
  float* perp = idxo + (size_t)RQDEPTH * NN;     // scalar

  float* resid = (float*)d_ws;                   // N*C
  float* cbT   = resid + PLANE;                  // C*K
  float* Arow  = cbT + (size_t)CC * KK;          // N
  float* Bcol  = Arow + NN;                      // K
  int* idxAll  = (int*)(Bcol + KK);              // D*N
  int* counts  = idxAll + RQDEPTH * NN;          // K

  dim3 tgrid(HWt / 32, CC / 32, BB);             // 32 x 8 x 32
  k_ztrans<<<tgrid, 256, 0, stream>>>(z, resid);
  dim3 cgrid(KK / 32, CC / 32);
  k_cbtrans<<<cgrid, 256, 0, stream>>>(cb, cbT);
  k_bnorm<<<KK / 256, 256, 0, stream>>>(cb, Bcol);
  k_zero<<<(KK + 255) / 256, 256, 0, stream>>>(counts);

  for (int d = 0; d < RQDEPTH; ++d) {
    k_anorm<<<NN / 256, 256, 0, stream>>>(resid, Arow);
    k_bulk<<<NN / 16, 256, 0, stream>>>(resid, cbT, Arow, Bcol, idxAll,
                                        idxo + (size_t)d * NN, counts, d);
    k_update<<<tgrid, 256, 0, stream>>>(cb, idxAll, resid, cum, zst, d);
  }
  k_perp<<<1, 256, 0, stream>>>(counts, perp);
}

// Round 5
// 2131.326 us; speedup vs baseline: 2.7275x; 2.7275x over previous
//
#include <hip/hip_runtime.h>
#include <math.h>

#define BB 32
#define CC 256
#define HWt 1024          // H*W
#define NN 32768          // B*H*W
#define KK 2048
#define RQDEPTH 4

// ===== numpy pairwise sum-of-squares, blocksize-128 tree, bit-exact =====
__device__ __forceinline__ float pw128sq(const float4* __restrict__ a4) {
  float r[8];
  {
    float4 p = a4[0], q = a4[1];
    r[0] = __fmul_rn(p.x, p.x); r[1] = __fmul_rn(p.y, p.y);
    r[2] = __fmul_rn(p.z, p.z); r[3] = __fmul_rn(p.w, p.w);
    r[4] = __fmul_rn(q.x, q.x); r[5] = __fmul_rn(q.y, q.y);
    r[6] = __fmul_rn(q.z, q.z); r[7] = __fmul_rn(q.w, q.w);
  }
  for (int i = 1; i < 16; ++i) {
    float4 p = a4[2 * i], q = a4[2 * i + 1];
    r[0] = __fadd_rn(r[0], __fmul_rn(p.x, p.x));
    r[1] = __fadd_rn(r[1], __fmul_rn(p.y, p.y));
    r[2] = __fadd_rn(r[2], __fmul_rn(p.z, p.z));
    r[3] = __fadd_rn(r[3], __fmul_rn(p.w, p.w));
    r[4] = __fadd_rn(r[4], __fmul_rn(q.x, q.x));
    r[5] = __fadd_rn(r[5], __fmul_rn(q.y, q.y));
    r[6] = __fadd_rn(r[6], __fmul_rn(q.z, q.z));
    r[7] = __fadd_rn(r[7], __fmul_rn(q.w, q.w));
  }
  return __fadd_rn(__fadd_rn(__fadd_rn(r[0], r[1]), __fadd_rn(r[2], r[3])),
                   __fadd_rn(__fadd_rn(r[4], r[5]), __fadd_rn(r[6], r[7])));
}

// ---------------- prep: z [B,C,H,W] -> resid [N,C] ----------------
__global__ void k_ztrans(const float* __restrict__ z, float* __restrict__ resid) {
  __shared__ float tile[32][33];
  int b = blockIdx.z, c0 = blockIdx.y * 32, hw0 = blockIdx.x * 32;
  int tx = threadIdx.x & 31, ty = threadIdx.x >> 5;
  for (int i = ty; i < 32; i += 8)
    tile[i][tx] = z[((size_t)b * CC + c0 + i) * HWt + hw0 + tx];
  __syncthreads();
  for (int i = ty; i < 32; i += 8)
    resid[((size_t)b * HWt + hw0 + i) * CC + c0 + tx] = tile[tx][i];
}

// ---------------- prep: cb [K,C] -> cbT [C,K] ----------------
__global__ void k_cbtrans(const float* __restrict__ cb, float* __restrict__ cbT) {
  __shared__ float tile[32][33];
  int k0 = blockIdx.x * 32, c0 = blockIdx.y * 32;
  int tx = threadIdx.x & 31, ty = threadIdx.x >> 5;
  for (int i = ty; i < 32; i += 8)
    tile[i][tx] = cb[(size_t)(k0 + i) * CC + c0 + tx];
  __syncthreads();
  for (int i = ty; i < 32; i += 8)
    cbT[(size_t)(c0 + i) * KK + k0 + tx] = tile[tx][i];
}

// ---------------- B_k = np.sum(cb**2, axis=1) bit-exact ----------------
__global__ void k_bnorm(const float* __restrict__ cb, float* __restrict__ Bcol) {
  int k = blockIdx.x * 256 + threadIdx.x;
  if (k >= KK) return;
  const float4* row = (const float4*)(cb + (size_t)k * CC);
  Bcol[k] = __fadd_rn(pw128sq(row), pw128sq(row + 32));
}

// ---------------- A_n = np.sum(resid**2, axis=1) bit-exact ----------------
__global__ void k_anorm(const float* __restrict__ resid, float* __restrict__ Arow) {
  int n = blockIdx.x * 256 + threadIdx.x;
  if (n >= NN) return;
  const float4* row = (const float4*)(resid + (size_t)n * CC);
  Arow[n] = __fadd_rn(pw128sq(row), pw128sq(row + 32));
}

__global__ void k_zero(int* counts) {
  int t = blockIdx.x * 256 + threadIdx.x;
  if (t < KK) counts[t] = 0;
}

// ---------------- bulk: np fp32 dists + first-argmin ----------------
// z served from a 16 KB LDS tile (uniform-address ds_read_b128 broadcast, in-
// order, fine-grained lgkmcnt) instead of round-0's 16 wave-uniform s_load per
// iteration (SMEM is out-of-order -> mandatory lgkmcnt(0) drain each iteration
// + scalar-cache thrash across 3 resident blocks). Spill control (the round-3
// failure): the 16-row FMA body is split into 4 groups of 4 rows with
// __builtin_amdgcn_sched_barrier(0x64) after each group -- SALU(0x4) +
// VMEM_READ(0x20) + VMEM_WRITE(0x40) may cross (e-load pipelining untouched),
// VALU and DS are pinned -> at most 4 z-float4 (16 VGPRs) live at once.
// Per-(n,k) fp32 chain is bit-identical to the verified kernel: strict
// c-ascending fmaf, fl(A+B) - 2*acc, u64 (dist,k) min == exact lex
// first-argmin. z bits are copied verbatim to LDS, so numerics are unchanged.
__global__ __launch_bounds__(256, 4) void k_bulk(const float* __restrict__ resid,
                                                 const float* __restrict__ cbT,
                                                 const float* __restrict__ Arow,
                                                 const float* __restrict__ Bcol,
                                                 int* __restrict__ idxAll,
                                                 float* __restrict__ idxOut,
                                                 int* __restrict__ counts, int depth) {
  __shared__ float zl[16 * 256];                 // 16 KiB z tile
  __shared__ unsigned long long sm[4][2][16];
  const int wave = __builtin_amdgcn_readfirstlane((int)(threadIdx.x >> 6));
  const int lane = threadIdx.x & 63;
  const int row0 = blockIdx.x * 16;

  // stage z tile -> LDS (coalesced float4, 4 per thread)
  {
    const float4* src = (const float4*)(resid + (size_t)row0 * CC);
    float4* dst = (float4*)zl;
#pragma unroll
    for (int i = 0; i < 4; ++i)
      dst[threadIdx.x + 256 * i] = src[threadIdx.x + 256 * i];
  }

  float av[16];
#pragma unroll
  for (int r = 0; r < 16; ++r) av[r] = Arow[row0 + r];   // uniform -> SGPR

  __syncthreads();

  for (int pass = 0; pass < 2; ++pass) {
    const int kbase = wave * 512 + pass * 256;
    float acc[16][4];
#pragma unroll
    for (int r = 0; r < 16; ++r)
#pragma unroll
      for (int j = 0; j < 4; ++j) acc[r][j] = 0.f;

    for (int c4 = 0; c4 < CC / 4; ++c4) {
      float e[16];  // [cs][j]
#pragma unroll
      for (int cs = 0; cs < 4; ++cs)
        *(float4*)(e + 4 * cs) =
            ((const float4*)(cbT + (size_t)(4 * c4 + cs) * KK + kbase))[lane];
#pragma unroll
      for (int rq = 0; rq < 4; ++rq) {
#pragma unroll
        for (int rr = 0; rr < 4; ++rr) {
          const int r = rq * 4 + rr;
          const float4 z4 = *(const float4*)(zl + r * 256 + 4 * c4);  // LDS broadcast
#pragma unroll
          for (int j = 0; j < 4; ++j) {
            float a = acc[r][j];
            a = fmaf(z4.x, e[0 * 4 + j], a);   // strict c-ascending chain
            a = fmaf(z4.y, e[1 * 4 + j], a);
            a = fmaf(z4.z, e[2 * 4 + j], a);
            a = fmaf(z4.w, e[3 * 4 + j], a);
            acc[r][j] = a;
          }
        }
        // liveness fence: VALU + DS pinned; SALU/VMEM may cross
        __builtin_amdgcn_sched_barrier(0x64);
      }
    }
    // epilogue: dists + exact lex first-argmin for this pass
    float bk[4];
    *(float4*)bk = ((const float4*)(Bcol + kbase))[lane];
#pragma unroll
    for (int r = 0; r < 16; ++r) {
      unsigned long long b = ~0ull;
#pragma unroll
      for (int j = 0; j < 4; ++j) {
        float Cv = __fadd_rn(av[r], bk[j]);                      // fl32(A + B)
        float s  = __fsub_rn(Cv, __fadd_rn(acc[r][j], acc[r][j]));  // fl32(C - 2M)
        unsigned long long pk =
            ((unsigned long long)__float_as_uint(s) << 32) |
            (unsigned int)(kbase + lane * 4 + j);
        if (pk < b) b = pk;
      }
      for (int m = 1; m < 64; m <<= 1) {
        unsigned long long o = __shfl_xor(b, m);
        if (o < b) b = o;
      }
      if (lane == 0) sm[wave][pass][r] = b;
    }
  }
  __syncthreads();
  // merge 4 waves x 2 passes per row
  if (threadIdx.x < 16) {
    unsigned long long b = ~0ull;
#pragma unroll
    for (int w = 0; w < 4; ++w)
#pragma unroll
      for (int p = 0; p < 2; ++p)
        if (sm[w][p][threadIdx.x] < b) b = sm[w][p][threadIdx.x];
    int wi = (int)(unsigned int)(b & 0xffffffffu);
    int n = row0 + (int)threadIdx.x;
    idxAll[depth * NN + n] = wi;
    idxOut[n] = (float)wi;
    atomicAdd(counts + wi, 1);
  }
}

// ------- update: resid -= q (fp32, np order), cum[d] = cum[d-1] + q, zst at d=3 -------
__global__ void k_update(const float* __restrict__ cb, const int* __restrict__ idxAll,
                         float* __restrict__ resid, float* __restrict__ cum,
                         float* __restrict__ zst, int depth) {
  __shared__ float qt[32][33];
  __shared__ float rt[32][33];
  int b = blockIdx.z, c0 = blockIdx.y * 32, hw0 = blockIdx.x * 32;
  int tx = threadIdx.x & 31, ty = threadIdx.x >> 5;
  const int* idx = idxAll + depth * NN;
  for (int i = ty; i < 32; i += 8) {
    int n = b * HWt + hw0 + i;
    int kk = idx[n];
    size_t fo = (size_t)n * CC + c0 + tx;
    float q = cb[(size_t)kk * CC + c0 + tx];
    float r = __fsub_rn(resid[fo], q);
    resid[fo] = r;
    qt[i][tx] = q;
    rt[i][tx] = r;
  }
  __syncthreads();
  const size_t PLANE = (size_t)NN * CC;
  for (int i = ty; i < 32; i += 8) {
    size_t oo = ((size_t)b * CC + c0 + i) * HWt + hw0 + tx;
    float q = qt[tx][i];
    float prevv = (depth == 0) ? 0.f : cum[(size_t)(depth - 1) * PLANE + oo];
    cum[(size_t)depth * PLANE + oo] = __fadd_rn(prevv, q);
    if (depth == 3) zst[oo] = rt[tx][i];
  }
}

// ---------------- perplexity ----------------
__global__ void k_perp(const int* __restrict__ counts, float* __restrict__ out) {
  __shared__ double sh[256];
  double s = 0.0;
  for (int k = threadIdx.x; k < KK; k += 256) {
    int c = counts[k];
    if (c > 0) {
      double p = (double)c / (double)(RQDEPTH * NN);
      s += p * log(p);
    }
  }
  sh[threadIdx.x] = s;
  __syncthreads();
  for (int st = 128; st; st >>= 1) {
    if (threadIdx.x < st) sh[threadIdx.x] += sh[threadIdx.x + st];
    __syncthreads();
  }
  if (threadIdx.x == 0) out[0] = (float)exp(-sh[0]);
}

extern "C" void kernel_launch(void* const* d_in, const int* in_sizes, int n_in,
                              void* d_out, int out_size, void* d_ws, size_t ws_size,
                              hipStream_t stream) {
  const float* z  = (const float*)d_in[0];
  const float* cb = (const float*)d_in[1];
  float* out = (float*)d_out;
  const size_t PLANE = (size_t)NN * CC;          // 8,388,608
  float* cum  = out;                             // [4][B][C][H][W]
  float* zst  = out + (size_t)RQDEPTH * PLANE;   // [B][C][H][W]
  float* idxo = zst + PLANE;                     // [4][N]
  float* perp = idxo + (size_t)RQDEPTH * NN;     // scalar

  float* resid = (float*)d_ws;                   // N*C
  float* cbT   = resid + PLANE;                  // C*K
  float* Arow  = cbT + (size_t)CC * KK;          // N
  float* Bcol  = Arow + NN;                      // K
  int* idxAll  = (int*)(Bcol + KK);              // D*N
  int* counts  = idxAll + RQDEPTH * NN;          // K

  dim3 tgrid(HWt / 32, CC / 32, BB);             // 32 x 8 x 32
  k_ztrans<<<tgrid, 256, 0, stream>>>(z, resid);
  dim3 cgrid(KK / 32, CC / 32);
  k_cbtrans<<<cgrid, 256, 0, stream>>>(cb, cbT);
  k_bnorm<<<KK / 256, 256, 0, stream>>>(cb, Bcol);
  k_zero<<<(KK + 255) / 256, 256, 0, stream>>>(counts);

  for (int d = 0; d < RQDEPTH; ++d) {
    k_anorm<<<NN / 256, 256, 0, stream>>>(resid, Arow);
    k_bulk<<<NN / 16, 256, 0, stream>>>(resid, cbT, Arow, Bcol, idxAll,
                                        idxo + (size_t)d * NN, counts, d);
    k_update<<<tgrid, 256, 0, stream>>>(cb, idxAll, resid, cum, zst, d);
  }
  k_perp<<<1, 256, 0, stream>>>(counts, perp);
}

// Round 7
// 946.428 us; speedup vs baseline: 6.1422x; 2.2520x over previous
//
#include <hip/hip_runtime.h>
#include <math.h>

#define BB 32
#define CC 256
#define HWt 1024          // H*W
#define NN 32768          // B*H*W
#define KK 2048
#define RQDEPTH 4
#define CAP 64            // candidate list capacity per row
#define DELTA 1e-3f       // candidate window; rigorous need ~3.2e-4 (3x margin)

typedef __attribute__((ext_vector_type(8))) short short8;     // 8 bf16 (4 VGPR)
typedef __attribute__((ext_vector_type(16))) float f32x16;    // MFMA 32x32 acc

// ===== numpy pairwise sum-of-squares, blocksize-128 tree, bit-exact =====
__device__ __forceinline__ float pw128sq(const float4* __restrict__ a4) {
  float r[8];
  {
    float4 p = a4[0], q = a4[1];
    r[0] = __fmul_rn(p.x, p.x); r[1] = __fmul_rn(p.y, p.y);
    r[2] = __fmul_rn(p.z, p.z); r[3] = __fmul_rn(p.w, p.w);
    r[4] = __fmul_rn(q.x, q.x); r[5] = __fmul_rn(q.y, q.y);
    r[6] = __fmul_rn(q.z, q.z); r[7] = __fmul_rn(q.w, q.w);
  }
  for (int i = 1; i < 16; ++i) {
    float4 p = a4[2 * i], q = a4[2 * i + 1];
    r[0] = __fadd_rn(r[0], __fmul_rn(p.x, p.x));
    r[1] = __fadd_rn(r[1], __fmul_rn(p.y, p.y));
    r[2] = __fadd_rn(r[2], __fmul_rn(p.z, p.z));
    r[3] = __fadd_rn(r[3], __fmul_rn(p.w, p.w));
    r[4] = __fadd_rn(r[4], __fmul_rn(q.x, q.x));
    r[5] = __fadd_rn(r[5], __fmul_rn(q.y, q.y));
    r[6] = __fadd_rn(r[6], __fmul_rn(q.z, q.z));
    r[7] = __fadd_rn(r[7], __fmul_rn(q.w, q.w));
  }
  return __fadd_rn(__fadd_rn(__fadd_rn(r[0], r[1]), __fadd_rn(r[2], r[3])),
                   __fadd_rn(__fadd_rn(r[4], r[5]), __fadd_rn(r[6], r[7])));
}

// bf16 round-to-nearest-even (values here are finite, no NaN handling needed)
__device__ __forceinline__ unsigned short f2bf(float x) {
  unsigned u = __float_as_uint(x);
  return (unsigned short)((u + 0x7fffu + ((u >> 16) & 1u)) >> 16);
}
// monotone float<->uint order-preserving encode (for atomicMin on float)
__device__ __forceinline__ unsigned fenc(float f) {
  unsigned u = __float_as_uint(f);
  return (u & 0x80000000u) ? ~u : (u | 0x80000000u);
}
__device__ __forceinline__ float fdec(unsigned k) {
  return __uint_as_float((k & 0x80000000u) ? (k ^ 0x80000000u) : ~k);
}

// ---------------- prep: z [B,C,H,W] -> resid [N,C] ----------------
__global__ void k_ztrans(const float* __restrict__ z, float* __restrict__ resid) {
  __shared__ float tile[32][33];
  int b = blockIdx.z, c0 = blockIdx.y * 32, hw0 = blockIdx.x * 32;
  int tx = threadIdx.x & 31, ty = threadIdx.x >> 5;
  for (int i = ty; i < 32; i += 8)
    tile[i][tx] = z[((size_t)b * CC + c0 + i) * HWt + hw0 + tx];
  __syncthreads();
  for (int i = ty; i < 32; i += 8)
    resid[((size_t)b * HWt + hw0 + i) * CC + c0 + tx] = tile[tx][i];
}

// ---------------- prep: codebook bf16 2-split in MFMA B-fragment order ------
// esX8[(kt*32 + c8)*32 + col] = 8 bf16 at c = c8*8 + i for codeword k = kt*32+col.
// Fragment load for (ktile, K-step, lane) is then 16B at a lane-consecutive
// address -> perfectly coalesced, L2-resident (2 x 1 MB).
__global__ void k_esplit(const float* __restrict__ cb, short8* __restrict__ esH8,
                         short8* __restrict__ esL8) {
  const int tg = blockIdx.x * 256 + threadIdx.x;   // 65536 = 2048 k * 32 c8
  const int k = tg >> 5, c8 = tg & 31;
  const int idx8 = ((k >> 5) * 32 + c8) * 32 + (k & 31);
  short8 H, L;
#pragma unroll
  for (int i = 0; i < 8; ++i) {
    float x = cb[(size_t)k * CC + c8 * 8 + i];
    unsigned short h = f2bf(x);
    float hf = __uint_as_float(((unsigned)h) << 16);
    unsigned short l = f2bf(__fsub_rn(x, hf));   // x-hf exact (Sterbenz)
    H[i] = (short)h; L[i] = (short)l;
  }
  esH8[idx8] = H; esL8[idx8] = L;
}

// ---------------- B_k = np.sum(cb**2, axis=1) bit-exact ----------------
__global__ void k_bnorm(const float* __restrict__ cb, float* __restrict__ Bcol) {
  int k = blockIdx.x * 256 + threadIdx.x;
  if (k >= KK) return;
  const float4* row = (const float4*)(cb + (size_t)k * CC);
  Bcol[k] = __fadd_rn(pw128sq(row), pw128sq(row + 32));
}

// ---------------- A_n = np.sum(resid**2, axis=1) bit-exact ----------------
__global__ void k_anorm(const float* __restrict__ resid, float* __restrict__ Arow) {
  int n = blockIdx.x * 256 + threadIdx.x;
  if (n >= NN) return;
  const float4* row = (const float4*)(resid + (size_t)n * CC);
  Arow[n] = __fadd_rn(pw128sq(row), pw128sq(row + 32));
}

__global__ void k_zero(int* counts) {
  int t = blockIdx.x * 256 + threadIdx.x;
  if (t < KK) counts[t] = 0;
}

// ---------------- bulk: MFMA-pruned exact argmin ----------------
// Phase 1 (MFMA): M~ = xh*eh + xh*el + xl*eh in fp32 MFMA accs; d~ = B - 2M~.
//   |d~ - (s - A)| <= ~1.6e-4 (2x ulp(512) quantization of the exact path +
//   split/accum error ~4e-5, with Sum|x_c e_c| <= sqrt(A*B) <= 0.25). A/B
//   fragment k-slot convention is identical for both operands -> contraction
//   is invariant to the hw slot->k bijection; C/D decode col=lane&31,
//   row=(reg&3)+8*(reg>>2)+4*(lane>>5) (HW-verified m74/m101). Online per-row
//   threshold thr = min(d~) + DELTA collects a guaranteed SUPERSET of
//   {k : s_k could lex-beat}: ref winner k* has d~(k*) <= d~min + 3.2e-4 << DELTA.
// Phase 2 (exact): for each candidate, the byte-identical fp32 path of the
//   verified kernel: strict c-ascending fmaf chain, fl(A+B) - 2*acc, u64
//   (dist,k) lex-min -> winner == reference winner exactly (ties at the
//   ulp(512) grid resolved by smallest-k, same as reference argmin).
__global__ __launch_bounds__(512, 4) void k_bulk(
    const float* __restrict__ resid, const short8* __restrict__ esH8,
    const short8* __restrict__ esL8, const float* __restrict__ cb,
    const float* __restrict__ Arow, const float* __restrict__ Bcol,
    int* __restrict__ idxAll, float* __restrict__ idxOut,
    int* __restrict__ counts, int depth) {
  __shared__ short8 zH8[32 * 32];          // [c8][row], 16 KB
  __shared__ short8 zL8[32 * 32];          // 16 KB
  __shared__ float zf[32 * 260];           // fp32 rows, +4 pad vs bank degeneracy
  __shared__ int cnt[32];
  __shared__ unsigned minkey[32];
  __shared__ unsigned long long best[32];
  __shared__ int clist[32 * CAP];

  const int t = threadIdx.x;
  const int row0 = blockIdx.x * 32;

  if (t < 32) { cnt[t] = 0; minkey[t] = 0xFFFFFFFFu; best[t] = ~0ull; }

  // ---- stage fp32 z tile ----
  {
    const int row = t >> 4;
    const int c4b = t & 15;
    const float4* src = (const float4*)(resid + (size_t)(row0 + row) * CC);
#pragma unroll
    for (int g = 0; g < 4; ++g) {
      const int c4i = c4b + 16 * g;
      *(float4*)(zf + row * 260 + c4i * 4) = src[c4i];
    }
  }
  __syncthreads();
  // ---- bf16 2-split into A-fragment layout [c8][row] ----
  {
    const int srow = t & 31;
    const int c8a = (t >> 5) * 2;
#pragma unroll
    for (int cc = 0; cc < 2; ++cc) {
      const int c8 = c8a + cc;
      short8 H, L;
#pragma unroll
      for (int i = 0; i < 8; ++i) {
        float x = zf[srow * 260 + c8 * 8 + i];
        unsigned short h = f2bf(x);
        float hf = __uint_as_float(((unsigned)h) << 16);
        unsigned short l = f2bf(__fsub_rn(x, hf));
        H[i] = (short)h; L[i] = (short)l;
      }
      zH8[c8 * 32 + srow] = H;             // lane-consecutive 16B: conflict-free
      zL8[c8 * 32 + srow] = L;
    }
  }
  __syncthreads();

  const int wave = t >> 6, lane = t & 63;
  const int l31 = lane & 31, hh = lane >> 5;

#define LOADF(AH, AL, EH, EL, STEP)                                            \
  { const int o_ = ((STEP) * 2 + hh) * 32 + l31;                               \
    AH = zH8[o_]; AL = zL8[o_];                                                \
    EH = esH8[kt * 1024 + o_]; EL = esL8[kt * 1024 + o_]; }

#pragma unroll 1
  for (int it = 0; it < 8; ++it) {
    const int kt = wave * 8 + it, kb = kt * 32;
    f32x16 a0, a1;
#pragma unroll
    for (int i = 0; i < 16; ++i) { a0[i] = 0.f; a1[i] = 0.f; }

    short8 cah, cal, ceh, cel, nah, nal, neh, nel;
    LOADF(cah, cal, ceh, cel, 0)
#pragma unroll
    for (int step = 0; step < 16; ++step) {
      if (step < 15) LOADF(nah, nal, neh, nel, step + 1)
      a0 = __builtin_amdgcn_mfma_f32_32x32x16_bf16(cah, ceh, a0, 0, 0, 0);
      a1 = __builtin_amdgcn_mfma_f32_32x32x16_bf16(cah, cel, a1, 0, 0, 0);
      a1 = __builtin_amdgcn_mfma_f32_32x32x16_bf16(cal, ceh, a1, 0, 0, 0);
      __builtin_amdgcn_sched_barrier(0);   // liveness fence: <=2 frag sets live
      if (step < 15) { cah = nah; cal = nal; ceh = neh; cel = nel; }
    }

    const float bkv = Bcol[kb + l31];
    float dt[16];
#pragma unroll
    for (int r = 0; r < 16; ++r) {
      const float m = __fadd_rn(a0[r], a1[r]);
      dt[r] = __fsub_rn(bkv, __fadd_rn(m, m));
    }
    if (it == 0) {
      // seed per-row min (so thresholds are finite before any append test)
#pragma unroll
      for (int r = 0; r < 16; ++r) {
        float rm = dt[r];
#pragma unroll
        for (int m = 1; m < 32; m <<= 1) rm = fminf(rm, __shfl_xor(rm, m));
        if (l31 == 0) {
          const int rowr = (r & 3) + 8 * (r >> 2) + 4 * hh;
          atomicMin(&minkey[rowr], fenc(rm));
        }
      }
    }
#pragma unroll
    for (int r = 0; r < 16; ++r) {
      const int rowr = (r & 3) + 8 * (r >> 2) + 4 * hh;
      const float thr = fdec(minkey[rowr]) + DELTA;   // stale-high = superset
      if (dt[r] <= thr) {
        atomicMin(&minkey[rowr], fenc(dt[r]));
        int idx = atomicAdd(&cnt[rowr], 1);
        if (idx < CAP) clist[rowr * CAP + idx] = kb + l31;
      }
    }
  }
  __syncthreads();

  // ---- exact recheck of candidates (byte-identical fp32 path) ----
  {
    const int row = t >> 4;
    const int nc0 = cnt[row];
    const int nc = nc0 < CAP ? nc0 : CAP;
    const float av = Arow[row0 + row];
    const float* zr = zf + row * 260;
    for (int s = (t & 15); s < nc; s += 16) {
      const int k = clist[row * CAP + s];
      const float4* e4 = (const float4*)(cb + (size_t)k * CC);
      float a = 0.f;
#pragma unroll 8
      for (int c4 = 0; c4 < 64; ++c4) {
        const float4 z4 = *(const float4*)(zr + c4 * 4);
        const float4 q4 = e4[c4];
        a = fmaf(z4.x, q4.x, a);            // strict c-ascending chain
        a = fmaf(z4.y, q4.y, a);
        a = fmaf(z4.z, q4.z, a);
        a = fmaf(z4.w, q4.w, a);
      }
      const float Cv = __fadd_rn(av, Bcol[k]);            // fl32(A + B)
      const float sv = __fsub_rn(Cv, __fadd_rn(a, a));    // fl32(C - 2M)
      unsigned long long pk =
          ((unsigned long long)__float_as_uint(sv) << 32) | (unsigned)k;
      atomicMin(&best[row], pk);
    }
  }
  __syncthreads();
  if (t < 32) {
    const int wi = (int)(unsigned)(best[t] & 0xffffffffu);
    const int n = row0 + t;
    idxAll[depth * NN + n] = wi;
    idxOut[n] = (float)wi;
    atomicAdd(counts + wi, 1);
  }
}

// ------- update: resid -= q (fp32, np order), cum[d] = cum[d-1] + q, zst at d=3 -------
__global__ void k_update(const float* __restrict__ cb, const int* __restrict__ idxAll,
                         float* __restrict__ resid, float* __restrict__ cum,
                         float* __restrict__ zst, int depth) {
  __shared__ float qt[32][33];
  __shared__ float rt[32][33];
  int b = blockIdx.z, c0 = blockIdx.y * 32, hw0 = blockIdx.x * 32;
  int tx = threadIdx.x & 31, ty = threadIdx.x >> 5;
  const int* idx = idxAll + depth * NN;
  for (int i = ty; i < 32; i += 8) {
    int n = b * HWt + hw0 + i;
    int kk = idx[n];
    size_t fo = (size_t)n * CC + c0 + tx;
    float q = cb[(size_t)kk * CC + c0 + tx];
    float r = __fsub_rn(resid[fo], q);
    resid[fo] = r;
    qt[i][tx] = q;
    rt[i][tx] = r;
  }
  __syncthreads();
  const size_t PLANE = (size_t)NN * CC;
  for (int i = ty; i < 32; i += 8) {
    size_t oo = ((size_t)b * CC + c0 + i) * HWt + hw0 + tx;
    float q = qt[tx][i];
    float prevv = (depth == 0) ? 0.f : cum[(size_t)(depth - 1) * PLANE + oo];
    cum[(size_t)depth * PLANE + oo] = __fadd_rn(prevv, q);
    if (depth == 3) zst[oo] = rt[tx][i];
  }
}

// ---------------- perplexity ----------------
__global__ void k_perp(const int* __restrict__ counts, float* __restrict__ out) {
  __shared__ double sh[256];
  double s = 0.0;
  for (int k = threadIdx.x; k < KK; k += 256) {
    int c = counts[k];
    if (c > 0) {
      double p = (double)c / (double)(RQDEPTH * NN);
      s += p * log(p);
    }
  }
  sh[threadIdx.x] = s;
  __syncthreads();
  for (int st = 128; st; st >>= 1) {
    if (threadIdx.x < st) sh[threadIdx.x] += sh[threadIdx.x + st];
    __syncthreads();
  }
  if (threadIdx.x == 0) out[0] = (float)exp(-sh[0]);
}

extern "C" void kernel_launch(void* const* d_in, const int* in_sizes, int n_in,
                              void* d_out, int out_size, void* d_ws, size_t ws_size,
                              hipStream_t stream) {
  const float* z  = (const float*)d_in[0];
  const float* cb = (const float*)d_in[1];
  float* out = (float*)d_out;
  const size_t PLANE = (size_t)NN * CC;          // 8,388,608
  float* cum  = out;                             // [4][B][C][H][W]
  float* zst  = out + (size_t)RQDEPTH * PLANE;   // [B][C][H][W]
  float* idxo = zst + PLANE;                     // [4][N]
  float* perp = idxo + (size_t)RQDEPTH * NN;     // scalar

  float* resid = (float*)d_ws;                   // N*C floats
  float* esbase = resid + PLANE;                 // 2 MB region (old cbT slot)
  short8* esH8 = (short8*)esbase;                // 1 MB: 65536 short8
  short8* esL8 = esH8 + 65536;                   // 1 MB
  float* Arow  = esbase + (size_t)CC * KK;       // N
  float* Bcol  = Arow + NN;                      // K
  int* idxAll  = (int*)(Bcol + KK);              // D*N
  int* counts  = idxAll + RQDEPTH * NN;          // K

  dim3 tgrid(HWt / 32, CC / 32, BB);             // 32 x 8 x 32
  k_ztrans<<<tgrid, 256, 0, stream>>>(z, resid);
  k_esplit<<<256, 256, 0, stream>>>(cb, esH8, esL8);
  k_bnorm<<<KK / 256, 256, 0, stream>>>(cb, Bcol);
  k_zero<<<(KK + 255) / 256, 256, 0, stream>>>(counts);

  for (int d = 0; d < RQDEPTH; ++d) {
    k_anorm<<<NN / 256, 256, 0, stream>>>(resid, Arow);
    k_bulk<<<NN / 32, 512, 0, stream>>>(resid, esH8, esL8, cb, Arow, Bcol,
                                        idxAll, idxo + (size_t)d * NN, counts, d);
    k_update<<<tgrid, 256, 0, stream>>>(cb, idxAll, resid, cum, zst, d);
  }
  k_perp<<<1, 256, 0, stream>>>(counts, perp);
}